// Round 8
// baseline (351.655 us; speedup 1.0000x reference)
//
#include <hip/hip_runtime.h>

#define MTOT 65536   // B*V
#define KTOT 1024    // F
#define NTOT 1024    // U

#define BM 256
#define BN 256
#define BK 32
#define NSTEP (KTOT / BK)   // 32

typedef __attribute__((ext_vector_type(4))) unsigned int u32x4;
typedef __attribute__((ext_vector_type(4))) float f32x4;
typedef __attribute__((ext_vector_type(8))) __bf16 bf16x8;

static __device__ __forceinline__ unsigned short f2bf(float f) {
    unsigned int u = __float_as_uint(f);
    u += 0x7fffu + ((u >> 16) & 1u);   // round-to-nearest-even
    return (unsigned short)(u >> 16);
}

static __device__ __forceinline__ bf16x8 cvt8(f32x4 a, f32x4 b) {
    bf16x8 r;
    r[0] = (__bf16)a[0]; r[1] = (__bf16)a[1]; r[2] = (__bf16)a[2]; r[3] = (__bf16)a[3];
    r[4] = (__bf16)b[0]; r[5] = (__bf16)b[1]; r[6] = (__bf16)b[2]; r[7] = (__bf16)b[3];
    return r;
}

#define GLOAD16(g, l)                                                              \
    __builtin_amdgcn_global_load_lds(                                              \
        (const __attribute__((address_space(1))) void*)(g),                        \
        (__attribute__((address_space(3))) void*)(l), 16, 0, 0)

#define VMCNT(n) asm volatile("s_waitcnt vmcnt(" #n ")" ::: "memory")
#define LGKM0    asm volatile("s_waitcnt lgkmcnt(0)" ::: "memory")
#define CFENCE   asm volatile("" ::: "memory")
#define BAR()    __builtin_amdgcn_s_barrier()

// ---- prep 1: valid[row] from adjacency only (33.5 MB read, ~6 us) ----
__global__ __launch_bounds__(256) void valid_kernel(const int* __restrict__ adj,
                                                    unsigned char* __restrict__ valid) {
    const int row  = blockIdx.x * 4 + (threadIdx.x >> 6);
    const int lane = threadIdx.x & 63;
    const int2 v = reinterpret_cast<const int2*>(adj)[(size_t)row * 64 + lane];
    const int anyv = __any((v.x >= 0) || (v.y >= 0));
    if (lane == 0) valid[row] = anyv ? 1 : 0;
}

// ---- prep 2: kT[n][k] = bf16(kern[k][n]) ----
__global__ __launch_bounds__(256) void transposeB_kernel(const float* __restrict__ kern,
                                                         unsigned short* __restrict__ kT) {
    __shared__ float tile[32][33];
    const int bx = blockIdx.x & 31;
    const int by = blockIdx.x >> 5;
    const int tx = threadIdx.x & 31;
    const int ty = threadIdx.x >> 5;
#pragma unroll
    for (int r = 0; r < 4; ++r)
        tile[ty + r * 8][tx] = kern[(size_t)(by * 32 + ty + r * 8) * NTOT + bx * 32 + tx];
    __syncthreads();
#pragma unroll
    for (int r = 0; r < 4; ++r)
        kT[(size_t)(bx * 32 + ty + r * 8) * KTOT + by * 32 + tx] = f2bf(tile[tx][ty + r * 8]);
}

// ---- main GEMM: 256x256, BK=32, 16 waves (4Mx4N, 64x64 each), quad-buffer ----
// A fp32 [M][K] (features, read directly), Bt bf16 [N][K].
// A staging: fp32 global->regs (step t, tile t+3) -> cvt+ds_write (step t+1, into
// buf[(t+3)&3]) -> read at step t+3.  B staging: global_load_lds (round-7 verified).
// vmcnt ledger (per-thread issue [A,A,B] each step, queue <=7):
//   steady vmcnt(4) confirms B(t+1) [in LDS for next step] + A(t+2)x2 [regs for
//   this step's AWRITE]; leaves B(t+2), A(t+3)x2, B(t+3) in flight — never 0.
//   Tail: t=29 -> vmcnt(1), t=30 -> vmcnt(0).  Compiler reorders of the C++
//   loads are safe: reg uses are compiler-guarded, LDS guards sit on the oldest
//   queue entries.
// WAR: AWRITE at t hits buf read at t-2 (two barriers); B-DMA at t hits buf read
// at t-1 (one barrier; reads drained by that step's LGKM0).  Same as round 7.
__global__ __launch_bounds__(1024, 4) void gemm_kernel(const float* __restrict__ A,
                                                       const unsigned short* __restrict__ Bt,
                                                       const float* __restrict__ bias,
                                                       const unsigned char* __restrict__ valid,
                                                       float* __restrict__ out) {
    __shared__ __align__(16) unsigned short Asm[4 * 8192];   // 4 bufs x 256x32 bf16
    __shared__ __align__(16) unsigned short Bsm[4 * 8192];

    const int tid  = threadIdx.x;
    const int lane = tid & 63;
    const int wv   = tid >> 6;     // 0..15
    const int wm   = wv >> 2;      // wave M quarter (rows wm*64..+64)
    const int wn   = wv & 3;       // wave N quarter (cols wn*64..+64)

    // bijective XCD swizzle (nwg = 1024, divisible by 8)
    const int cpx = (int)gridDim.x >> 3;
    const int swz = ((int)blockIdx.x & 7) * cpx + ((int)blockIdx.x >> 3);
    const int bm  = swz >> 2;      // 0..255
    const int bn  = swz & 3;       // 0..3
    const size_t m0 = (size_t)bm * BM;
    const int    n0 = bn * BN;

    // staging: thread covers tile row tid>>2, phys 16B chunk tid&3;
    // source logical chunk = phys ^ ((row>>1)&3)  (involution, verified r2/r7)
    const int srow = tid >> 2;
    const int lch  = (tid & 3) ^ ((tid >> 3) & 3);
    const int s_loff = wv << 9;                     // wave-uniform LDS base (ush)
    const int awd    = tid * 8;                     // ds_write dest (ush) within buf

    const unsigned short* Bgl = Bt + (size_t)n0 * KTOT + (size_t)srow * KTOT + lch * 8;
    const float*          agl = A  + (m0 + srow) * (size_t)KTOT + lch * 8;

#define STAGE_B(b, kt) GLOAD16(Bgl + (kt) * BK, &Bsm[(b) * 8192 + s_loff])
#define ALOAD(s, kt) do {                                                          \
        asr[s][0] = *reinterpret_cast<const f32x4*>(agl + (kt) * BK);              \
        asr[s][1] = *reinterpret_cast<const f32x4*>(agl + (kt) * BK + 4);          \
    } while (0)
#define AWRITE(b, s)                                                               \
    *reinterpret_cast<bf16x8*>(&Asm[(b) * 8192 + awd]) = cvt8(asr[s][0], asr[s][1])

    // fragment read addressing: phys = logical(g4) ^ ((lr>>1)&3)
    const int lr  = lane & 15;
    const int g4  = lane >> 4;
    const int rsw = (g4 ^ ((lr >> 1) & 3)) << 3;
    int aridx[4], bridx[4];
#pragma unroll
    for (int m = 0; m < 4; ++m)
        aridx[m] = (wm * 64 + m * 16 + lr) * BK + rsw;
#pragma unroll
    for (int n = 0; n < 4; ++n)
        bridx[n] = (wn * 64 + n * 16 + lr) * BK + rsw;

    f32x4 acc[4][4];
#pragma unroll
    for (int m = 0; m < 4; ++m)
#pragma unroll
        for (int n = 0; n < 4; ++n)
            acc[m][n] = {0.0f, 0.0f, 0.0f, 0.0f};

    f32x4 asr[2][2];

    // prologue: A0,A1 -> regs; B0,B1,B2 DMA; confirm A0,A1; write A0->buf0,
    // A1->buf1; load A2 regs; confirm B0; barrier.
    ALOAD(0, 0); ALOAD(1, 1);
    STAGE_B(0, 0); STAGE_B(1, 1); STAGE_B(2, 2);
    VMCNT(3);
    AWRITE(0, 0); AWRITE(1, 1);
    ALOAD(1, 2);
    VMCNT(4);
    LGKM0; BAR(); CFENCE;

#pragma unroll
    for (int t = 0; t < NSTEP; ++t) {
        if (t + 3 < NSTEP) { ALOAD(t & 1, t + 3); STAGE_B((t + 3) & 3, t + 3); }
        const int b = t & 3;
        bf16x8 af[4], bfr[4];
#pragma unroll
        for (int n = 0; n < 4; ++n)
            bfr[n] = __builtin_bit_cast(bf16x8, *reinterpret_cast<const u32x4*>(&Bsm[b * 8192 + bridx[n]]));
#pragma unroll
        for (int m = 0; m < 4; ++m)
            af[m] = __builtin_bit_cast(bf16x8, *reinterpret_cast<const u32x4*>(&Asm[b * 8192 + aridx[m]]));
        __builtin_amdgcn_s_setprio(1);
#pragma unroll
        for (int m = 0; m < 4; ++m)
#pragma unroll
            for (int n = 0; n < 4; ++n)
                acc[m][n] = __builtin_amdgcn_mfma_f32_16x16x32_bf16(af[m], bfr[n], acc[m][n], 0, 0, 0);
        __builtin_amdgcn_s_setprio(0);
        if (t == 0)              VMCNT(3);
        else if (t <= NSTEP - 4) VMCNT(4);
        else if (t == NSTEP - 3) VMCNT(1);
        else if (t == NSTEP - 2) VMCNT(0);
        if (t + 2 < NSTEP) AWRITE((t + 2) & 3, (t + 1) & 1);
        if (t < NSTEP - 1) { LGKM0; BAR(); CFENCE; }
    }

    // epilogue: C/D layout col=lane&15, row=(lane>>4)*4+q
    // valid rows: relu(acc+bias); invalid rows: passthrough features (K==N, L2-hot)
    float bv[4];
#pragma unroll
    for (int n = 0; n < 4; ++n)
        bv[n] = bias[n0 + wn * 64 + n * 16 + lr];

#pragma unroll
    for (int m = 0; m < 4; ++m) {
#pragma unroll
        for (int q = 0; q < 4; ++q) {
            const size_t row = m0 + wm * 64 + m * 16 + g4 * 4 + q;
            const size_t ro  = row * NTOT + n0 + wn * 64 + lr;
            if (valid[row]) {
#pragma unroll
                for (int n = 0; n < 4; ++n)
                    out[ro + n * 16] = fmaxf(acc[m][n][q] + bv[n], 0.0f);
            } else {
#pragma unroll
                for (int n = 0; n < 4; ++n)
                    out[ro + n * 16] = A[ro + n * 16];
            }
        }
    }
#undef STAGE_B
#undef ALOAD
#undef AWRITE
}

extern "C" void kernel_launch(void* const* d_in, const int* in_sizes, int n_in,
                              void* d_out, int out_size, void* d_ws, size_t ws_size,
                              hipStream_t stream) {
    const int*   adj  = (const int*)d_in[0];
    const float* feat = (const float*)d_in[1];
    const float* kern = (const float*)d_in[2];
    const float* bias = (const float*)d_in[3];
    float* out = (float*)d_out;

    unsigned short* kT    = (unsigned short*)d_ws;                      // 2 MB
    unsigned char*  valid = (unsigned char*)d_ws + 2 * 1024 * 1024;     // 64 KB

    valid_kernel<<<MTOT / 4, 256, 0, stream>>>(adj, valid);
    transposeB_kernel<<<(KTOT / 32) * (NTOT / 32), 256, 0, stream>>>(kern, kT);
    gemm_kernel<<<(MTOT / BM) * (NTOT / BN), 1024, 0, stream>>>(feat, kT, bias, valid, out);
}